// Round 1
// baseline (60.878 us; speedup 1.0000x reference)
//
#include <hip/hip_runtime.h>

// CapsuleRoutingPooling collapses analytically:
//   softmax over a singleton axis (axis=3, size 1) == 1.0 always, so the
//   routing logits `b` never affect anything. Output is simply
//   squash(2x2 sum-pool of D=16 vectors).
// Shapes (fixed by setup_inputs): B=16, C=64, H=64, W=64, D=16, k=2.
//   nH=nW=32, output = (B,C,32,32,16) float32.

#define B_  16
#define C_  64
#define H_  64
#define W_  64
#define D_  16
#define NH_ 32
#define NW_ 32

__global__ __launch_bounds__(256)
void caps_pool_squash_kernel(const float* __restrict__ in, float* __restrict__ out) {
    const unsigned tid = blockIdx.x * 256u + threadIdx.x;
    const unsigned vec = tid >> 2;   // output vector index in [0, B*C*NH*NW)
    const unsigned q   = tid & 3u;   // which float4 of the D=16 vector

    const unsigned bc  = vec >> 10;        // b*C + c   (NH*NW = 1024)
    const unsigned rem = vec & 1023u;
    const unsigned nh  = rem >> 5;         // NW = 32
    const unsigned nw  = rem & 31u;

    // input element index of (bc, h=2*nh, w=2*nw, d=4*q)
    const unsigned base = ((bc * H_ + 2u * nh) * W_ + 2u * nw) * D_ + q * 4u;

    const float4 a = *(const float4*)(in + base);                  // (h, w)
    const float4 b = *(const float4*)(in + base + D_);             // (h, w+1)
    const float4 c = *(const float4*)(in + base + W_ * D_);        // (h+1, w)
    const float4 d = *(const float4*)(in + base + W_ * D_ + D_);   // (h+1, w+1)

    float4 s;
    s.x = (a.x + b.x) + (c.x + d.x);
    s.y = (a.y + b.y) + (c.y + d.y);
    s.z = (a.z + b.z) + (c.z + d.z);
    s.w = (a.w + b.w) + (c.w + d.w);

    // squared norm over D=16: partial per lane, butterfly over the 4 quad lanes
    float p = s.x * s.x + s.y * s.y + s.z * s.z + s.w * s.w;
    p += __shfl_xor(p, 1, 64);
    p += __shfl_xor(p, 2, 64);

    // squash scale: sq/(1+sq) * 1/(sqrt(sq)+1e-8)
    const float scale = p / ((1.0f + p) * (sqrtf(p) + 1e-8f));

    float4 v;
    v.x = s.x * scale;
    v.y = s.y * scale;
    v.z = s.z * scale;
    v.w = s.w * scale;

    *(float4*)(out + vec * (unsigned)D_ + q * 4u) = v;
}

extern "C" void kernel_launch(void* const* d_in, const int* in_sizes, int n_in,
                              void* d_out, int out_size, void* d_ws, size_t ws_size,
                              hipStream_t stream) {
    const float* inp = (const float*)d_in[0];
    float* out = (float*)d_out;

    const unsigned nvec    = B_ * C_ * NH_ * NW_;   // 1,048,576 output vectors
    const unsigned threads = nvec * 4u;             // 4 threads per vector
    const unsigned blocks  = threads / 256u;        // 16384

    caps_pool_squash_kernel<<<blocks, 256, 0, stream>>>(inp, out);
}